// Round 1
// baseline (714.347 us; speedup 1.0000x reference)
//
#include <hip/hip_runtime.h>
#include <math.h>

#define BB 16
#define CC 256
#define NN 9216        // 96*96
#define NCHUNK 72      // k_kv chunks per image (2 tiles of 64 each)
#define EPSV 1e-5f
#define LSTR 68        // padded LDS row stride in floats (64 data + 4 pad)

// ---- workspace layout (float offsets) ----
#define WS_SUMS  0                          // [B][C][2]  per-channel sum, sumsq
#define WS_AB    (WS_SUMS + BB*CC*2)        // [B][C][2]  affine a, b  (xn = a*x+b)
#define WS_GATE  (WS_AB + BB*CC*2)          // [B]
#define WS_MPART (WS_GATE + BB)             // [B][72][1024]
#define WS_ZPART (WS_MPART + BB*NCHUNK*1024)// [B][72][64]
#define WS_MF    (WS_ZPART + BB*NCHUNK*64)  // [B][1024]
#define WS_ZF    (WS_MF + BB*1024)          // [B][64]
// total ≈ 1,287,184 floats ≈ 5.15 MB

#define AXPY4(acc, s, v) do { (acc).x += (s)*(v).x; (acc).y += (s)*(v).y; \
                              (acc).z += (s)*(v).z; (acc).w += (s)*(v).w; } while(0)

__device__ __forceinline__ float elup1(float v) { return v > 0.f ? v + 1.f : expf(v); }

// ---------------- kernel 1: per-channel sums ----------------
__global__ __launch_bounds__(256) void k_stats(const float* __restrict__ x,
                                               float* __restrict__ ws) {
  const int bc = blockIdx.x;                     // b*C + c
  const float4* p4 = (const float4*)(x + (size_t)bc * NN);
  float s = 0.f, s2 = 0.f;
  for (int i = threadIdx.x; i < NN/4; i += 256) {
    float4 v = p4[i];
    s  += v.x + v.y + v.z + v.w;
    s2 += v.x*v.x + v.y*v.y + v.z*v.z + v.w*v.w;
  }
  for (int off = 32; off > 0; off >>= 1) {
    s  += __shfl_down(s,  off);
    s2 += __shfl_down(s2, off);
  }
  __shared__ float rs[4], rs2[4];
  const int wid = threadIdx.x >> 6, lane = threadIdx.x & 63;
  if (lane == 0) { rs[wid] = s; rs2[wid] = s2; }
  __syncthreads();
  if (threadIdx.x == 0) {
    ws[WS_SUMS + bc*2]     = rs[0]+rs[1]+rs[2]+rs[3];
    ws[WS_SUMS + bc*2 + 1] = rs2[0]+rs2[1]+rs2[2]+rs2[3];
  }
}

// ---------------- kernel 2: group stats -> affine, pooled, gate ----------------
__global__ __launch_bounds__(256) void k_prep(const float* __restrict__ norm_w,
                                              const float* __restrict__ norm_b,
                                              const float* __restrict__ Wg1,
                                              const float* __restrict__ bg1,
                                              const float* __restrict__ Wg2,
                                              const float* __restrict__ bg2,
                                              float* __restrict__ ws,
                                              float* __restrict__ out) {
  const int b = blockIdx.x, c = threadIdx.x;     // 256 threads == C
  const float s  = ws[WS_SUMS + (b*CC+c)*2];
  const float s2 = ws[WS_SUMS + (b*CC+c)*2 + 1];
  // group reduce: 32 consecutive channels per group; lanes 0-31 / 32-63 halves
  float gs = s, gs2 = s2;
  for (int off = 1; off < 32; off <<= 1) {
    gs  += __shfl_xor(gs,  off);
    gs2 += __shfl_xor(gs2, off);
  }
  const float inv = 1.0f / (32.0f * (float)NN);
  const float mu  = gs * inv;
  const float var = gs2 * inv - mu*mu;
  const float rstd = rsqrtf(var + EPSV);
  const float w = norm_w[c], nb = norm_b[c];
  const float a   = w * rstd;
  const float bbv = nb - w * mu * rstd;
  ws[WS_AB + (b*CC+c)*2]     = a;
  ws[WS_AB + (b*CC+c)*2 + 1] = bbv;

  __shared__ float pooled[CC];
  __shared__ float g1[64];
  pooled[c] = fmaf(a, s * (1.0f/(float)NN), bbv);
  __syncthreads();
  if (c < 64) {
    float acc = bg1[c];
    const float* wr = Wg1 + c*CC;
    for (int i = 0; i < CC; ++i) acc = fmaf(wr[i], pooled[i], acc);
    g1[c] = 0.5f * acc * (1.0f + erff(acc * 0.70710678118654752f));  // exact GELU
  }
  __syncthreads();
  if (c == 0) {
    float acc = bg2[0];
    for (int o = 0; o < 64; ++o) acc = fmaf(Wg2[o], g1[o], acc);
    const float gate = 1.0f / (1.0f + expf(-acc));
    ws[WS_GATE + b] = gate;
    out[(size_t)BB*CC*NN + b] = gate;            // gate output (tuple tail)
  }
}

// ---------------- kernel 3: k,v projection + partial M,Z ----------------
__global__ __launch_bounds__(256) void k_kv(const float* __restrict__ x,
                                            const float* __restrict__ Wk,
                                            const float* __restrict__ Wv,
                                            float* __restrict__ ws) {
  const int chunk = blockIdx.x;                  // 0..71
  const int b = blockIdx.y;
  const int tid = threadIdx.x;
  __shared__ float lds[CC*LSTR];                 // xn tile, later phi_k(rows 0..63)+v(64..127)
  __shared__ float alds[CC], blds[CC];
  alds[tid] = ws[WS_AB + (b*CC+tid)*2];
  blds[tid] = ws[WS_AB + (b*CC+tid)*2 + 1];

  const int to = tid >> 4, tt = tid & 15;
  const int obase = to*8;                        // 8 outputs (o) per thread, 128 total
  const int tb = tt*4;                           // 4 t per thread
  const float4* Wm4 = (obase < 64) ? (const float4*)Wk : (const float4*)Wv;
  const int orow = (obase < 64) ? obase : (obase - 64);

  const int idx0 = tid*4;                        // 4 M-entries per thread
  const int mh = idx0 >> 8, md = (idx0 >> 4) & 15, me0 = idx0 & 15;

  float macc0=0.f, macc1=0.f, macc2=0.f, macc3=0.f;
  float zacc = 0.f;
  const int cc0 = tid >> 4, t4 = tid & 15;

  for (int tile = 0; tile < 2; ++tile) {
    const int n0 = chunk*128 + tile*64;
    __syncthreads();                             // protect lds reuse
    #pragma unroll
    for (int ci = 0; ci < 16; ++ci) {
      const int c = ci*16 + cc0;
      float4 xv = *(const float4*)(x + (size_t)(b*CC + c)*NN + n0 + t4*4);
      const float a = alds[c], bbv = blds[c];
      float4 r;
      r.x = fmaf(a, xv.x, bbv); r.y = fmaf(a, xv.y, bbv);
      r.z = fmaf(a, xv.z, bbv); r.w = fmaf(a, xv.w, bbv);
      *(float4*)&lds[c*LSTR + t4*4] = r;
    }
    __syncthreads();

    // GEMM: [128 o] x [64 t] = Wkv[128][256] * xn[256][64]
    float4 acc[8];
    #pragma unroll
    for (int i = 0; i < 8; ++i) acc[i] = make_float4(0.f,0.f,0.f,0.f);
    for (int c4 = 0; c4 < 64; ++c4) {
      const float4 xv0 = *(const float4*)&lds[(c4*4+0)*LSTR + tb];
      const float4 xv1 = *(const float4*)&lds[(c4*4+1)*LSTR + tb];
      const float4 xv2 = *(const float4*)&lds[(c4*4+2)*LSTR + tb];
      const float4 xv3 = *(const float4*)&lds[(c4*4+3)*LSTR + tb];
      #pragma unroll
      for (int i = 0; i < 8; ++i) {
        const float4 wv = Wm4[(orow+i)*64 + c4];
        AXPY4(acc[i], wv.x, xv0);
        AXPY4(acc[i], wv.y, xv1);
        AXPY4(acc[i], wv.z, xv2);
        AXPY4(acc[i], wv.w, xv3);
      }
    }
    __syncthreads();                             // all xn reads done
    if (obase < 64) {                            // wave-uniform branch
      #pragma unroll
      for (int i = 0; i < 8; ++i) {
        float4 p;
        p.x = elup1(acc[i].x); p.y = elup1(acc[i].y);
        p.z = elup1(acc[i].z); p.w = elup1(acc[i].w);
        *(float4*)&lds[(obase+i)*LSTR + tb] = p;     // phi_k rows 0..63
      }
    } else {
      #pragma unroll
      for (int i = 0; i < 8; ++i)
        *(float4*)&lds[(obase+i)*LSTR + tb] = acc[i]; // v rows 64..127
    }
    __syncthreads();

    // partial M[h][d][e] += sum_t phi_k[h*16+d][t] * v[h*16+e][t]; 4 entries/thread
    {
      const float* phrow = &lds[(mh*16+md)*LSTR];
      const float* v0 = &lds[(64 + mh*16 + me0 + 0)*LSTR];
      const float* v1 = &lds[(64 + mh*16 + me0 + 1)*LSTR];
      const float* v2 = &lds[(64 + mh*16 + me0 + 2)*LSTR];
      const float* v3 = &lds[(64 + mh*16 + me0 + 3)*LSTR];
      #pragma unroll
      for (int q = 0; q < 16; ++q) {
        const float4 ph = *(const float4*)&phrow[q*4];
        const float4 a0 = *(const float4*)&v0[q*4];
        const float4 a1 = *(const float4*)&v1[q*4];
        const float4 a2 = *(const float4*)&v2[q*4];
        const float4 a3 = *(const float4*)&v3[q*4];
        macc0 += ph.x*a0.x + ph.y*a0.y + ph.z*a0.z + ph.w*a0.w;
        macc1 += ph.x*a1.x + ph.y*a1.y + ph.z*a1.z + ph.w*a1.w;
        macc2 += ph.x*a2.x + ph.y*a2.y + ph.z*a2.z + ph.w*a2.w;
        macc3 += ph.x*a3.x + ph.y*a3.y + ph.z*a3.z + ph.w*a3.w;
      }
      if (tid < 64) {                            // Z[h][d] partial
        const float* pr = &lds[tid*LSTR];
        #pragma unroll
        for (int q = 0; q < 16; ++q) {
          const float4 p = *(const float4*)&pr[q*4];
          zacc += p.x + p.y + p.z + p.w;
        }
      }
    }
  }
  {
    float* mp = ws + WS_MPART + ((size_t)b*NCHUNK + chunk)*1024 + idx0;
    mp[0] = macc0; mp[1] = macc1; mp[2] = macc2; mp[3] = macc3;
    if (tid < 64) ws[WS_ZPART + ((size_t)b*NCHUNK + chunk)*64 + tid] = zacc;
  }
}

// ---------------- kernel 4: reduce partials, add M0/Z0 ----------------
__global__ __launch_bounds__(256) void k_reduce(const float* __restrict__ M0,
                                                const float* __restrict__ Z0,
                                                float* __restrict__ ws) {
  const int b = blockIdx.x, tid = threadIdx.x;
  const int idx0 = tid*4;
  float4 s = *(const float4*)(M0 + idx0);
  for (int ch = 0; ch < NCHUNK; ++ch) {
    const float4 p = *(const float4*)&ws[WS_MPART + ((size_t)b*NCHUNK + ch)*1024 + idx0];
    s.x += p.x; s.y += p.y; s.z += p.z; s.w += p.w;
  }
  *(float4*)&ws[WS_MF + b*1024 + idx0] = s;
  if (tid < 64) {
    float z = Z0[tid];
    for (int ch = 0; ch < NCHUNK; ++ch)
      z += ws[WS_ZPART + ((size_t)b*NCHUNK + ch)*64 + tid];
    ws[WS_ZF + b*64 + tid] = z;
  }
}

// ---------------- kernel 5: q proj + retrieval + out conv + residual ----------------
__global__ __launch_bounds__(256) void k_out(const float* __restrict__ x,
                                             const float* __restrict__ Wq,
                                             const float* __restrict__ Wout,
                                             const float* __restrict__ bout,
                                             const float* __restrict__ ws,
                                             float* __restrict__ out) {
  const int tile = blockIdx.x;                   // 0..143
  const int b = blockIdx.y;
  const int tid = threadIdx.x;
  const int n0 = tile*64;
  __shared__ float lds[CC*LSTR];                 // xn; later phiq(rows 0..63) + y(rows 64..127)
  __shared__ float Ml[1024];
  __shared__ float Zl[64];
  __shared__ float alds[CC], blds[CC];
  alds[tid] = ws[WS_AB + (b*CC+tid)*2];
  blds[tid] = ws[WS_AB + (b*CC+tid)*2 + 1];
  {
    const float* mf = ws + WS_MF + b*1024;
    #pragma unroll
    for (int j = 0; j < 4; ++j) Ml[tid*4+j] = mf[tid*4+j];
    if (tid < 64) Zl[tid] = ws[WS_ZF + b*64 + tid];
  }
  const float gate = ws[WS_GATE + b];
  __syncthreads();

  const int cc0 = tid >> 4, t4 = tid & 15;
  #pragma unroll
  for (int ci = 0; ci < 16; ++ci) {
    const int c = ci*16 + cc0;
    float4 xv = *(const float4*)(x + (size_t)(b*CC + c)*NN + n0 + t4*4);
    const float a = alds[c], bbv = blds[c];
    float4 r;
    r.x = fmaf(a, xv.x, bbv); r.y = fmaf(a, xv.y, bbv);
    r.z = fmaf(a, xv.z, bbv); r.w = fmaf(a, xv.w, bbv);
    *(float4*)&lds[c*LSTR + t4*4] = r;
  }
  __syncthreads();

  // q GEMM: 64 o x 64 t ; thread: 4 o (to*4..), 4 t (tt*4..)
  const int to = tid >> 4, tt = tid & 15;
  const int tb = tt*4;
  float4 q0 = make_float4(0,0,0,0), q1 = q0, q2 = q0, q3 = q0;
  const float4* Wq4 = (const float4*)Wq;
  for (int c4 = 0; c4 < 64; ++c4) {
    const float4 xv0 = *(const float4*)&lds[(c4*4+0)*LSTR + tb];
    const float4 xv1 = *(const float4*)&lds[(c4*4+1)*LSTR + tb];
    const float4 xv2 = *(const float4*)&lds[(c4*4+2)*LSTR + tb];
    const float4 xv3 = *(const float4*)&lds[(c4*4+3)*LSTR + tb];
    const float4 w0 = Wq4[(to*4+0)*64 + c4];
    const float4 w1 = Wq4[(to*4+1)*64 + c4];
    const float4 w2 = Wq4[(to*4+2)*64 + c4];
    const float4 w3 = Wq4[(to*4+3)*64 + c4];
    AXPY4(q0, w0.x, xv0); AXPY4(q0, w0.y, xv1); AXPY4(q0, w0.z, xv2); AXPY4(q0, w0.w, xv3);
    AXPY4(q1, w1.x, xv0); AXPY4(q1, w1.y, xv1); AXPY4(q1, w1.z, xv2); AXPY4(q1, w1.w, xv3);
    AXPY4(q2, w2.x, xv0); AXPY4(q2, w2.y, xv1); AXPY4(q2, w2.z, xv2); AXPY4(q2, w2.w, xv3);
    AXPY4(q3, w3.x, xv0); AXPY4(q3, w3.y, xv1); AXPY4(q3, w3.z, xv2); AXPY4(q3, w3.w, xv3);
  }
  q0.x=elup1(q0.x); q0.y=elup1(q0.y); q0.z=elup1(q0.z); q0.w=elup1(q0.w);
  q1.x=elup1(q1.x); q1.y=elup1(q1.y); q1.z=elup1(q1.z); q1.w=elup1(q1.w);
  q2.x=elup1(q2.x); q2.y=elup1(q2.y); q2.z=elup1(q2.z); q2.w=elup1(q2.w);
  q3.x=elup1(q3.x); q3.y=elup1(q3.y); q3.z=elup1(q3.z); q3.w=elup1(q3.w);
  __syncthreads();                               // xn fully consumed
  *(float4*)&lds[(to*4+0)*LSTR + tb] = q0;       // phiq rows 0..63
  *(float4*)&lds[(to*4+1)*LSTR + tb] = q1;
  *(float4*)&lds[(to*4+2)*LSTR + tb] = q2;
  *(float4*)&lds[(to*4+3)*LSTR + tb] = q3;
  __syncthreads();

  // y[e][t] = (sum_d M[d][e] phiq[d][t]) / max(sum_d Z[d] phiq[d][t], 1e-4)
  {
    const int h = to >> 2;
    const int e0 = (to*4) & 15;
    float4 n0v = make_float4(0,0,0,0), n1v = n0v, n2v = n0v, n3v = n0v, den = n0v;
    #pragma unroll
    for (int d = 0; d < 16; ++d) {
      const float4 ph = *(const float4*)&lds[(h*16+d)*LSTR + tb];
      AXPY4(den, Zl[h*16+d], ph);
      const float* mrow = &Ml[h*256 + d*16 + e0];
      AXPY4(n0v, mrow[0], ph);
      AXPY4(n1v, mrow[1], ph);
      AXPY4(n2v, mrow[2], ph);
      AXPY4(n3v, mrow[3], ph);
    }
    den.x = fmaxf(den.x, 1e-4f); den.y = fmaxf(den.y, 1e-4f);
    den.z = fmaxf(den.z, 1e-4f); den.w = fmaxf(den.w, 1e-4f);
    float4 y0, y1, y2, y3;
    y0.x = n0v.x/den.x; y0.y = n0v.y/den.y; y0.z = n0v.z/den.z; y0.w = n0v.w/den.w;
    y1.x = n1v.x/den.x; y1.y = n1v.y/den.y; y1.z = n1v.z/den.z; y1.w = n1v.w/den.w;
    y2.x = n2v.x/den.x; y2.y = n2v.y/den.y; y2.z = n2v.z/den.z; y2.w = n2v.w/den.w;
    y3.x = n3v.x/den.x; y3.y = n3v.y/den.y; y3.z = n3v.z/den.z; y3.w = n3v.w/den.w;
    *(float4*)&lds[(64 + to*4+0)*LSTR + tb] = y0;  // y rows 64..127 (distinct region)
    *(float4*)&lds[(64 + to*4+1)*LSTR + tb] = y1;
    *(float4*)&lds[(64 + to*4+2)*LSTR + tb] = y2;
    *(float4*)&lds[(64 + to*4+3)*LSTR + tb] = y3;
  }
  __syncthreads();

  // out conv 256 c x 64 t ; thread: 4 c (cg*4..), 16 t (tg*16..)
  const int cg = tid >> 2, tg = tid & 3;
  float4 oa[4][4];
  #pragma unroll
  for (int i = 0; i < 4; ++i)
    #pragma unroll
    for (int q = 0; q < 4; ++q) oa[i][q] = make_float4(0,0,0,0);
  const float4* Wo4 = (const float4*)Wout;
  #pragma unroll 4
  for (int m4 = 0; m4 < 16; ++m4) {
    const float4 wv0 = Wo4[(cg*4+0)*16 + m4];
    const float4 wv1 = Wo4[(cg*4+1)*16 + m4];
    const float4 wv2 = Wo4[(cg*4+2)*16 + m4];
    const float4 wv3 = Wo4[(cg*4+3)*16 + m4];
#define OUTSTEP(WC, MM) { \
    const float* yr = &lds[(64 + m4*4 + MM)*LSTR + tg*16]; \
    const float4 ya = *(const float4*)&yr[0];  \
    const float4 yb = *(const float4*)&yr[4];  \
    const float4 yc = *(const float4*)&yr[8];  \
    const float4 yd = *(const float4*)&yr[12]; \
    AXPY4(oa[0][0], wv0.WC, ya); AXPY4(oa[0][1], wv0.WC, yb); AXPY4(oa[0][2], wv0.WC, yc); AXPY4(oa[0][3], wv0.WC, yd); \
    AXPY4(oa[1][0], wv1.WC, ya); AXPY4(oa[1][1], wv1.WC, yb); AXPY4(oa[1][2], wv1.WC, yc); AXPY4(oa[1][3], wv1.WC, yd); \
    AXPY4(oa[2][0], wv2.WC, ya); AXPY4(oa[2][1], wv2.WC, yb); AXPY4(oa[2][2], wv2.WC, yc); AXPY4(oa[2][3], wv2.WC, yd); \
    AXPY4(oa[3][0], wv3.WC, ya); AXPY4(oa[3][1], wv3.WC, yb); AXPY4(oa[3][2], wv3.WC, yc); AXPY4(oa[3][3], wv3.WC, yd); }
    OUTSTEP(x, 0)
    OUTSTEP(y, 1)
    OUTSTEP(z, 2)
    OUTSTEP(w, 3)
#undef OUTSTEP
  }
  // epilogue: out = x + gate*(conv + bout)
  #pragma unroll
  for (int i = 0; i < 4; ++i) {
    const int c = cg*4 + i;
    const float bo = bout[c];
    const float* xb = x   + (size_t)(b*CC + c)*NN + n0 + tg*16;
    float*       ob = out + (size_t)(b*CC + c)*NN + n0 + tg*16;
    #pragma unroll
    for (int q = 0; q < 4; ++q) {
      const float4 xg = *(const float4*)(xb + q*4);
      const float4 v = oa[i][q];
      float4 r;
      r.x = fmaf(gate, v.x + bo, xg.x);
      r.y = fmaf(gate, v.y + bo, xg.y);
      r.z = fmaf(gate, v.z + bo, xg.z);
      r.w = fmaf(gate, v.w + bo, xg.w);
      *(float4*)(ob + q*4) = r;
    }
  }
}

extern "C" void kernel_launch(void* const* d_in, const int* in_sizes, int n_in,
                              void* d_out, int out_size, void* d_ws, size_t ws_size,
                              hipStream_t stream) {
  (void)in_sizes; (void)n_in; (void)out_size; (void)ws_size;
  const float* x      = (const float*)d_in[0];
  const float* norm_w = (const float*)d_in[1];
  const float* norm_b = (const float*)d_in[2];
  const float* Wk     = (const float*)d_in[3];
  const float* Wv     = (const float*)d_in[4];
  const float* Wq     = (const float*)d_in[5];
  const float* Wout   = (const float*)d_in[6];
  const float* bout   = (const float*)d_in[7];
  const float* M0     = (const float*)d_in[8];
  const float* Z0     = (const float*)d_in[9];
  const float* Wg1    = (const float*)d_in[10];
  const float* bg1    = (const float*)d_in[11];
  const float* Wg2    = (const float*)d_in[12];
  const float* bg2    = (const float*)d_in[13];
  float* out = (float*)d_out;
  float* ws  = (float*)d_ws;

  hipLaunchKernelGGL(k_stats,  dim3(BB*CC),      dim3(256), 0, stream, x, ws);
  hipLaunchKernelGGL(k_prep,   dim3(BB),         dim3(256), 0, stream,
                     norm_w, norm_b, Wg1, bg1, Wg2, bg2, ws, out);
  hipLaunchKernelGGL(k_kv,     dim3(NCHUNK, BB), dim3(256), 0, stream, x, Wk, Wv, ws);
  hipLaunchKernelGGL(k_reduce, dim3(BB),         dim3(256), 0, stream, M0, Z0, ws);
  hipLaunchKernelGGL(k_out,    dim3(144, BB),    dim3(256), 0, stream,
                     x, Wq, Wout, bout, ws, out);
}